// Round 18
// baseline (1868.478 us; speedup 1.0000x reference)
//
#include <hip/hip_runtime.h>
#include <stdint.h>

#define Bb    4
#define EMBED 96
#define NCH   3
#define Hh    512
#define Ww    512
#define HWSZ  (Hh * Ww)
#define KN    49152
#define NPT   16384
#define NIMP  12288
#define NCOV  4096
#define RTILE 8192

// Opaque register fence: compiler cannot contract or reassociate across it.
__device__ __forceinline__ float opaque(float v) {
    asm volatile("" : "+v"(v));
    return v;
}

// ---------- coords (all ops EXACT for grid-aligned p = k*2^-23; no fence needed) ----------
__device__ __forceinline__ void ref_coords(float p, int& i0, float& w0, float& w1) {
    float g  = 2.0f * p - 1.0f;
    float t  = (g + 1.0f) * 512.0f - 1.0f;
    float ix = t * 0.5f;
    float f  = floorf(ix);
    i0 = (int)f;
    w1 = ix - f;
    w0 = 1.0f - w1;
}

// order-preserving map: u32 ascending == float descending (bijective)
__device__ __forceinline__ uint32_t sortable_desc32(float v) {
    uint32_t u = __float_as_uint(v);
    uint32_t asc = (u >> 31) ? ~u : (u ^ 0x80000000u);
    return ~asc;
}

// ---------- kernel 1: TRUE strict-sequential f32 uncertainty (fenced, uncontracted) ----------
__global__ void uncert32_kernel(const float* __restrict__ res,
                                const float* __restrict__ outm,
                                const float* __restrict__ over_gen,
                                uint32_t* __restrict__ uk) {
    int lb = blockIdx.y;
    int i  = blockIdx.x * blockDim.x + threadIdx.x;   // < KN

    float px = over_gen[((size_t)lb * KN + i) * 2 + 0];
    float py = over_gen[((size_t)lb * KN + i) * 2 + 1];
    int x0, y0;
    float wx0, wx1, wy0, wy1;
    ref_coords(px, x0, wx0, wx1);
    ref_coords(py, y0, wy0, wy1);

    const float* r0 = res  + (size_t)lb * NCH * HWSZ;
    const float* o0 = outm + (size_t)lb * NCH * HWSZ;

    int   cxs[4] = {x0, x0 + 1, x0, x0 + 1};
    int   cys[4] = {y0, y0, y0 + 1, y0 + 1};
    float wxs[4] = {wx0, wx1, wx0, wx1};
    float wys[4] = {wy0, wy0, wy1, wy1};

    float acc0 = 0.0f, acc1 = 0.0f;
#pragma unroll
    for (int q = 0; q < 4; ++q) {
        int xq = cxs[q], yq = cys[q];
        if (xq < 0 || xq >= Ww || yq < 0 || yq >= Hh) continue;   // zero term
        int off = yq * Ww + xq;
        // each op individually rounded; fences forbid fma contraction
        float d0 = opaque(o0[off]            - r0[off]);
        float d1 = opaque(o0[HWSZ + off]     - r0[HWSZ + off]);
        float d2 = opaque(o0[2 * HWSZ + off] - r0[2 * HWSZ + off]);
        float a  = opaque(d0 * d0);
        float bq = opaque(d1 * d1);
        float c  = opaque(d2 * d2);
        float m0 = fmaxf(fmaxf(a, bq), c);                        // max (exact select)
        float m1 = fmaxf(fminf(a, bq), fminf(fmaxf(a, bq), c));   // median (exact select)
        float wq = opaque(wxs[q] * wys[q]);
        float t0 = opaque(wq * m0);
        float t1 = opaque(wq * m1);
        acc0 = opaque(acc0 + t0);
        acc1 = opaque(acc1 + t1);
    }
    uk[(size_t)lb * KN + i] = sortable_desc32(opaque(acc1 - acc0));
}

// ---------- kernel 2: counting rank (asc-index ties = stable top_k) ----------
__global__ void __launch_bounds__(256) rank_kernel(const uint32_t* __restrict__ uk,
                                                   uint32_t* __restrict__ sel) {
    __shared__ uint32_t tile[RTILE];
    int lb = blockIdx.y;
    int i  = blockIdx.x * blockDim.x + threadIdx.x;
    const uint32_t* ub = uk + (size_t)lb * KN;
    uint32_t ki = ub[i];
    int cnt = 0;
    for (int t0 = 0; t0 < KN; t0 += RTILE) {
        for (int s = threadIdx.x; s < RTILE; s += 256)
            tile[s] = ub[t0 + s];
        __syncthreads();
#pragma unroll 8
        for (int s = 0; s < RTILE; ++s) {
            uint32_t kj = tile[s];
            int j = t0 + s;
            cnt += (int)((kj < ki) | ((kj == ki) & (j < i)));
        }
        __syncthreads();
    }
    if (cnt < NIMP) sel[(size_t)lb * NIMP + cnt] = (uint32_t)i;
}

// ---------- kernel 3: gather 99-ch features, 3x99 matvec + relu ----------
__global__ void render_kernel(const float* __restrict__ x,
                              const float* __restrict__ outm,
                              const float* __restrict__ w_mlp,
                              const float* __restrict__ over_gen,
                              const float* __restrict__ coverage,
                              const uint32_t* __restrict__ sel,
                              float* __restrict__ dst) {
    int gid = blockIdx.x * blockDim.x + threadIdx.x;
    int pt = gid >> 3, r = gid & 7;
    int lb = blockIdx.y;
    int n  = pt;                     // < NPT

    float px, py;
    if (n < NIMP) {
        uint32_t idx = sel[(size_t)lb * NIMP + n];
        if (idx >= KN) idx = 0;
        px = over_gen[((size_t)lb * KN + idx) * 2 + 0];
        py = over_gen[((size_t)lb * KN + idx) * 2 + 1];
    } else {
        int m = n - NIMP;
        px = coverage[((size_t)lb * NCOV + m) * 2 + 0];
        py = coverage[((size_t)lb * NCOV + m) * 2 + 1];
    }

    int x0, y0;
    float wx0, wx1, wy0, wy1;
    ref_coords(px, x0, wx0, wx1);
    ref_coords(py, y0, wy0, wy1);

    int   cxs[4] = {x0, x0 + 1, x0, x0 + 1};
    int   cys[4] = {y0, y0, y0 + 1, y0 + 1};
    float wcs[4] = {wx0 * wy0, wx1 * wy0, wx0 * wy1, wx1 * wy1};
    bool  vld[4];
#pragma unroll
    for (int q = 0; q < 4; ++q)
        vld[q] = (cxs[q] >= 0) & (cxs[q] < Ww) & (cys[q] >= 0) & (cys[q] < Hh);

    float acc0 = 0.0f, acc1 = 0.0f, acc2 = 0.0f;
    for (int c = r; c < NCH + EMBED; c += 8) {
        const float* src = (c < NCH)
            ? (outm + ((size_t)lb * NCH + c) * HWSZ)
            : (x + ((size_t)lb * EMBED + (c - NCH)) * HWSZ);
        float f = 0.0f;
#pragma unroll
        for (int q = 0; q < 4; ++q) {
            if (vld[q]) f += wcs[q] * src[cys[q] * Ww + cxs[q]];
        }
        acc0 += w_mlp[c] * f;
        acc1 += w_mlp[99 + c] * f;
        acc2 += w_mlp[198 + c] * f;
    }
#pragma unroll
    for (int d = 1; d < 8; d <<= 1) {
        acc0 += __shfl_xor(acc0, d);
        acc1 += __shfl_xor(acc1, d);
        acc2 += __shfl_xor(acc2, d);
    }
    if (r == 0) {
        size_t ob = (size_t)lb * 3 * NPT + n;
        dst[ob]           = fmaxf(acc0, 0.0f);
        dst[ob + NPT]     = fmaxf(acc1, 0.0f);
        dst[ob + 2 * NPT] = fmaxf(acc2, 0.0f);
    }
}

extern "C" void kernel_launch(void* const* d_in, const int* in_sizes, int n_in,
                              void* d_out, int out_size, void* d_ws, size_t ws_size,
                              hipStream_t stream) {
    const float* x        = (const float*)d_in[0];
    const float* res      = (const float*)d_in[1];
    const float* outm     = (const float*)d_in[2];
    const float* w_mlp    = (const float*)d_in[3];
    const float* over_gen = (const float*)d_in[4];
    const float* coverage = (const float*)d_in[5];
    float* dst = (float*)d_out;

    const size_t uk_sz = (size_t)Bb * KN * sizeof(uint32_t);   // 768 KiB

    uint32_t* uk  = (uint32_t*)d_ws;
    uint32_t* sel = (uint32_t*)((char*)d_ws + uk_sz);

    dim3 gU(KN / 256, Bb), gR(KN / 256, Bb), gD(NPT * 8 / 256, Bb);
    uncert32_kernel<<<gU, 256, 0, stream>>>(res, outm, over_gen, uk);
    rank_kernel<<<gR, 256, 0, stream>>>(uk, sel);
    render_kernel<<<gD, 256, 0, stream>>>(x, outm, w_mlp, over_gen, coverage, sel, dst);
}

// Round 19
// 422.244 us; speedup vs baseline: 4.4251x; 4.4251x over previous
//
#include <hip/hip_runtime.h>
#include <stdint.h>

#define Bb    4
#define EMBED 96
#define NCH   3
#define Hh    512
#define Ww    512
#define HWSZ  (Hh * Ww)
#define KN    49152      // K*N oversampled points
#define NPT   16384      // N final points
#define NIMP  12288      // importance points
#define NCOV  4096       // coverage points
#define SORTN 65536      // KN padded to power of two

// Opaque register fence: compiler cannot contract or reassociate across it.
// THIS IS THE CORRECTNESS-CRITICAL PIECE (R18): hipcc -ffp-contract=fast
// otherwise fuses mul+add into fma and the selection ranking diverges from
// the numpy reference at ulp level.
__device__ __forceinline__ float opaque(float v) {
    asm volatile("" : "+v"(v));
    return v;
}

// ---------- coords (all ops EXACT for grid-aligned p = k*2^-23; no fence needed) ----------
__device__ __forceinline__ void ref_coords(float p, int& i0, float& w0, float& w1) {
    float g  = 2.0f * p - 1.0f;
    float t  = (g + 1.0f) * 512.0f - 1.0f;
    float ix = t * 0.5f;
    float f  = floorf(ix);
    i0 = (int)f;
    w1 = ix - f;
    w0 = 1.0f - w1;
}

// order-preserving map: u32 ascending == float descending (bijective)
__device__ __forceinline__ uint32_t sortable_desc32(float v) {
    uint32_t u = __float_as_uint(v);
    uint32_t asc = (u >> 31) ? ~u : (u ^ 0x80000000u);
    return ~asc;
}

// ---------- kernel 1: fenced strict-f32 uncertainty -> packed u64 sort keys ----------
// key = (sortable_desc32(uncert) << 32) | index ; ascending u64 sort ==
// uncert descending, index ascending on ties == jax top_k order.
__global__ void uncert_keys(const float* __restrict__ res,
                            const float* __restrict__ outm,
                            const float* __restrict__ over_gen,
                            uint64_t* __restrict__ keys, int b0) {
    int lb = blockIdx.y;
    int b  = b0 + lb;
    int i  = blockIdx.x * blockDim.x + threadIdx.x;   // < SORTN
    if (i >= KN) { keys[(size_t)lb * SORTN + i] = 0xFFFFFFFFFFFFFFFFull; return; }

    float px = over_gen[((size_t)b * KN + i) * 2 + 0];
    float py = over_gen[((size_t)b * KN + i) * 2 + 1];
    int x0, y0;
    float wx0, wx1, wy0, wy1;
    ref_coords(px, x0, wx0, wx1);
    ref_coords(py, y0, wy0, wy1);

    const float* r0 = res  + (size_t)b * NCH * HWSZ;
    const float* o0 = outm + (size_t)b * NCH * HWSZ;

    int   cxs[4] = {x0, x0 + 1, x0, x0 + 1};
    int   cys[4] = {y0, y0, y0 + 1, y0 + 1};
    float wxs[4] = {wx0, wx1, wx0, wx1};
    float wys[4] = {wy0, wy0, wy1, wy1};

    float acc0 = 0.0f, acc1 = 0.0f;
#pragma unroll
    for (int q = 0; q < 4; ++q) {
        int xq = cxs[q], yq = cys[q];
        if (xq < 0 || xq >= Ww || yq < 0 || yq >= Hh) continue;   // zero term
        int off = yq * Ww + xq;
        // each op individually rounded; fences forbid fma contraction (R18)
        float d0 = opaque(o0[off]            - r0[off]);
        float d1 = opaque(o0[HWSZ + off]     - r0[HWSZ + off]);
        float d2 = opaque(o0[2 * HWSZ + off] - r0[2 * HWSZ + off]);
        float a  = opaque(d0 * d0);
        float bq = opaque(d1 * d1);
        float c  = opaque(d2 * d2);
        float m0 = fmaxf(fmaxf(a, bq), c);                        // max (exact select)
        float m1 = fmaxf(fminf(a, bq), fminf(fmaxf(a, bq), c));   // median (exact select)
        float wq = opaque(wxs[q] * wys[q]);
        float t0 = opaque(wq * m0);
        float t1 = opaque(wq * m1);
        acc0 = opaque(acc0 + t0);
        acc1 = opaque(acc1 + t1);
    }
    float u = opaque(acc1 - acc0);
    keys[(size_t)lb * SORTN + i] =
        ((uint64_t)sortable_desc32(u) << 32) | (uint32_t)i;
}

// ---------- bitonic sort over per-batch segments of SORTN ----------
// fused local kernel: stages k = 2..2048 entirely in LDS (2048-element tile)
__global__ void __launch_bounds__(1024) bitonic_local_first(uint64_t* __restrict__ keys) {
    __shared__ uint64_t sh[2048];
    uint64_t* base = keys + (size_t)blockIdx.x * 2048;
    int t = threadIdx.x;
    sh[t]        = base[t];
    sh[t + 1024] = base[t + 1024];
    __syncthreads();
    int gbase = (blockIdx.x & 31) << 11;   // element offset within batch segment
    for (int k = 2; k <= 2048; k <<= 1) {
        for (int j = k >> 1; j >= 1; j >>= 1) {
            int low = t & (j - 1);
            int i = ((t ^ low) << 1) | low;
            int l = i | j;
            bool up = (((gbase + i) & k) == 0);
            uint64_t a = sh[i], c = sh[l];
            if ((a > c) == up) { sh[i] = c; sh[l] = a; }
            __syncthreads();
        }
    }
    base[t]        = sh[t];
    base[t + 1024] = sh[t + 1024];
}

// one global compare-exchange pass (stride j >= 2048) of stage k
__global__ void bitonic_global(uint64_t* __restrict__ keys, int j, int k) {
    int t = blockIdx.x * blockDim.x + threadIdx.x;   // nb * SORTN/2 threads
    int b = t >> 15;
    int p = t & 32767;
    int low = p & (j - 1);
    int i = ((p ^ low) << 1) | low;
    int l = i | j;
    bool up = ((i & k) == 0);
    uint64_t* kb = keys + ((size_t)b << 16);
    uint64_t a = kb[i], c = kb[l];
    if ((a > c) == up) { kb[i] = c; kb[l] = a; }
}

// fused local tail of stage k: strides 1024..1 (direction constant per tile, k >= 4096)
__global__ void __launch_bounds__(1024) bitonic_local_k(uint64_t* __restrict__ keys, int k) {
    __shared__ uint64_t sh[2048];
    uint64_t* base = keys + (size_t)blockIdx.x * 2048;
    int t = threadIdx.x;
    sh[t]        = base[t];
    sh[t + 1024] = base[t + 1024];
    __syncthreads();
    int gbase = (blockIdx.x & 31) << 11;
    bool up = ((gbase & k) == 0);
    for (int j = 1024; j >= 1; j >>= 1) {
        int low = t & (j - 1);
        int i = ((t ^ low) << 1) | low;
        int l = i | j;
        uint64_t a = sh[i], c = sh[l];
        if ((a > c) == up) { sh[i] = c; sh[l] = a; }
        __syncthreads();
    }
    base[t]        = sh[t];
    base[t + 1024] = sh[t + 1024];
}

static void run_sort(uint64_t* keys, int nb, hipStream_t stream) {
    bitonic_local_first<<<nb * (SORTN / 2048), 1024, 0, stream>>>(keys);
    for (int k = 4096; k <= 65536; k <<= 1) {
        for (int j = k >> 1; j >= 2048; j >>= 1)
            bitonic_global<<<nb * (SORTN / 2) / 256, 256, 0, stream>>>(keys, j, k);
        bitonic_local_k<<<nb * (SORTN / 2048), 1024, 0, stream>>>(keys, k);
    }
}

// ---------- kernel 3: gather 99-ch features at final points, 3x99 matvec + relu ----------
__global__ void render_kernel(const float* __restrict__ x,
                              const float* __restrict__ outm,
                              const float* __restrict__ w_mlp,
                              const float* __restrict__ over_gen,
                              const float* __restrict__ coverage,
                              const uint64_t* __restrict__ keys,
                              float* __restrict__ dst, int b0) {
    int gid = blockIdx.x * blockDim.x + threadIdx.x;
    int pt = gid >> 3, r = gid & 7;
    int lb = blockIdx.y;
    int b  = b0 + lb;
    int n  = pt;                     // < NPT

    float px, py;
    if (n < NIMP) {
        uint32_t idx = (uint32_t)keys[((size_t)lb << 16) + n];   // low 32 = index
        if (idx >= KN) idx = 0;      // defensive
        px = over_gen[((size_t)b * KN + idx) * 2 + 0];
        py = over_gen[((size_t)b * KN + idx) * 2 + 1];
    } else {
        int m = n - NIMP;
        px = coverage[((size_t)b * NCOV + m) * 2 + 0];
        py = coverage[((size_t)b * NCOV + m) * 2 + 1];
    }

    int x0, y0;
    float wx0, wx1, wy0, wy1;
    ref_coords(px, x0, wx0, wx1);
    ref_coords(py, y0, wy0, wy1);

    int   cxs[4] = {x0, x0 + 1, x0, x0 + 1};
    int   cys[4] = {y0, y0, y0 + 1, y0 + 1};
    float wcs[4] = {wx0 * wy0, wx1 * wy0, wx0 * wy1, wx1 * wy1};
    bool  vld[4];
#pragma unroll
    for (int q = 0; q < 4; ++q)
        vld[q] = (cxs[q] >= 0) & (cxs[q] < Ww) & (cys[q] >= 0) & (cys[q] < Hh);

    float acc0 = 0.0f, acc1 = 0.0f, acc2 = 0.0f;
    for (int c = r; c < NCH + EMBED; c += 8) {
        const float* src = (c < NCH)
            ? (outm + ((size_t)b * NCH + c) * HWSZ)
            : (x + ((size_t)b * EMBED + (c - NCH)) * HWSZ);
        float f = 0.0f;
#pragma unroll
        for (int q = 0; q < 4; ++q) {
            if (vld[q]) f += wcs[q] * src[cys[q] * Ww + cxs[q]];
        }
        acc0 += w_mlp[c] * f;
        acc1 += w_mlp[99 + c] * f;
        acc2 += w_mlp[198 + c] * f;
    }
#pragma unroll
    for (int d = 1; d < 8; d <<= 1) {
        acc0 += __shfl_xor(acc0, d);
        acc1 += __shfl_xor(acc1, d);
        acc2 += __shfl_xor(acc2, d);
    }
    if (r == 0) {
        size_t ob = (size_t)b * 3 * NPT + n;
        dst[ob]           = fmaxf(acc0, 0.0f);
        dst[ob + NPT]     = fmaxf(acc1, 0.0f);
        dst[ob + 2 * NPT] = fmaxf(acc2, 0.0f);
    }
}

extern "C" void kernel_launch(void* const* d_in, const int* in_sizes, int n_in,
                              void* d_out, int out_size, void* d_ws, size_t ws_size,
                              hipStream_t stream) {
    const float* x        = (const float*)d_in[0];
    const float* res      = (const float*)d_in[1];
    const float* outm     = (const float*)d_in[2];
    const float* w_mlp    = (const float*)d_in[3];
    const float* over_gen = (const float*)d_in[4];
    const float* coverage = (const float*)d_in[5];
    float* dst = (float*)d_out;
    uint64_t* keys = (uint64_t*)d_ws;

    const size_t need_all = (size_t)Bb * SORTN * sizeof(uint64_t);  // 2 MiB

    if (ws_size >= need_all) {
        dim3 gU(SORTN / 256, Bb), gD(NPT * 8 / 256, Bb);
        uncert_keys<<<gU, 256, 0, stream>>>(res, outm, over_gen, keys, 0);
        run_sort(keys, Bb, stream);
        render_kernel<<<gD, 256, 0, stream>>>(x, outm, w_mlp, over_gen, coverage, keys, dst, 0);
    } else {
        // per-batch fallback: 512 KiB of keys
        dim3 gU(SORTN / 256, 1), gD(NPT * 8 / 256, 1);
        for (int b = 0; b < Bb; ++b) {
            uncert_keys<<<gU, 256, 0, stream>>>(res, outm, over_gen, keys, b);
            run_sort(keys, 1, stream);
            render_kernel<<<gD, 256, 0, stream>>>(x, outm, w_mlp, over_gen, coverage, keys, dst, b);
        }
    }
}

// Round 20
// 311.090 us; speedup vs baseline: 6.0062x; 1.3573x over previous
//
#include <hip/hip_runtime.h>
#include <stdint.h>

#define Bb    4
#define EMBED 96
#define NCH   3
#define Hh    512
#define Ww    512
#define HWSZ  (Hh * Ww)
#define KN    49152      // K*N oversampled points
#define NPT   16384      // N final points
#define NIMP  12288      // importance points
#define NCOV  4096       // coverage points
#define SORTN 65536      // KN padded to power of two

// Opaque register fence (R18 CORRECTNESS-CRITICAL): hipcc -ffp-contract=fast
// otherwise fuses mul+add into fma and the selection ranking diverges from
// the numpy reference at ulp level.
__device__ __forceinline__ float opaque(float v) {
    asm volatile("" : "+v"(v));
    return v;
}

// ---------- coords (all ops EXACT for grid-aligned p; no fence needed) ----------
__device__ __forceinline__ void ref_coords(float p, int& i0, float& w0, float& w1) {
    float g  = 2.0f * p - 1.0f;
    float t  = (g + 1.0f) * 512.0f - 1.0f;
    float ix = t * 0.5f;
    float f  = floorf(ix);
    i0 = (int)f;
    w1 = ix - f;
    w0 = 1.0f - w1;
}

__device__ __forceinline__ uint32_t sortable_desc32(float v) {
    uint32_t u = __float_as_uint(v);
    uint32_t asc = (u >> 31) ? ~u : (u ^ 0x80000000u);
    return ~asc;
}

__device__ __forceinline__ uint32_t part1by1(uint32_t v) {
    v &= 0xFFFFu;
    v = (v | (v << 8)) & 0x00FF00FFu;
    v = (v | (v << 4)) & 0x0F0F0F0Fu;
    v = (v | (v << 2)) & 0x33333333u;
    v = (v | (v << 1)) & 0x55555555u;
    return v;
}

// ---------- kernel 0: per-pixel (max, median) of squared diffs -> float2 map ----------
// Per-pixel ops identical (and identically rounded) to inline computation.
__global__ void build_maps(const float* __restrict__ res,
                           const float* __restrict__ outm,
                           float2* __restrict__ maps) {
    int lb  = blockIdx.y;
    int pix = blockIdx.x * blockDim.x + threadIdx.x;   // < HWSZ
    const float* r0 = res  + (size_t)lb * NCH * HWSZ;
    const float* o0 = outm + (size_t)lb * NCH * HWSZ;
    float d0 = opaque(o0[pix]            - r0[pix]);
    float d1 = opaque(o0[HWSZ + pix]     - r0[HWSZ + pix]);
    float d2 = opaque(o0[2 * HWSZ + pix] - r0[2 * HWSZ + pix]);
    float a  = opaque(d0 * d0);
    float bq = opaque(d1 * d1);
    float c  = opaque(d2 * d2);
    float m0 = fmaxf(fmaxf(a, bq), c);                        // max
    float m1 = fmaxf(fminf(a, bq), fminf(fmaxf(a, bq), c));   // median
    maps[(size_t)lb * HWSZ + pix] = make_float2(m0, m1);
}

// ---------- kernel 1a: fenced strict-f32 uncertainty via maps -> u64 sort keys ----------
__global__ void uncert_keys_maps(const float2* __restrict__ maps,
                                 const float* __restrict__ over_gen,
                                 uint64_t* __restrict__ keys) {
    int lb = blockIdx.y;
    int i  = blockIdx.x * blockDim.x + threadIdx.x;   // < SORTN
    if (i >= KN) { keys[(size_t)lb * SORTN + i] = 0xFFFFFFFFFFFFFFFFull; return; }

    float px = over_gen[((size_t)lb * KN + i) * 2 + 0];
    float py = over_gen[((size_t)lb * KN + i) * 2 + 1];
    int x0, y0;
    float wx0, wx1, wy0, wy1;
    ref_coords(px, x0, wx0, wx1);
    ref_coords(py, y0, wy0, wy1);

    const float2* mp = maps + (size_t)lb * HWSZ;
    int   cxs[4] = {x0, x0 + 1, x0, x0 + 1};
    int   cys[4] = {y0, y0, y0 + 1, y0 + 1};
    float wxs[4] = {wx0, wx1, wx0, wx1};
    float wys[4] = {wy0, wy0, wy1, wy1};

    float acc0 = 0.0f, acc1 = 0.0f;
#pragma unroll
    for (int q = 0; q < 4; ++q) {
        int xq = cxs[q], yq = cys[q];
        if (xq < 0 || xq >= Ww || yq < 0 || yq >= Hh) continue;   // zero term
        float2 m = mp[yq * Ww + xq];
        float wq = opaque(wxs[q] * wys[q]);
        float t0 = opaque(wq * m.x);
        float t1 = opaque(wq * m.y);
        acc0 = opaque(acc0 + t0);
        acc1 = opaque(acc1 + t1);
    }
    float u = opaque(acc1 - acc0);
    keys[(size_t)lb * SORTN + i] =
        ((uint64_t)sortable_desc32(u) << 32) | (uint32_t)i;
}

// ---------- kernel 1b: direct variant (fallback when ws can't hold maps) ----------
__global__ void uncert_keys_direct(const float* __restrict__ res,
                                   const float* __restrict__ outm,
                                   const float* __restrict__ over_gen,
                                   uint64_t* __restrict__ keys) {
    int lb = blockIdx.y;
    int i  = blockIdx.x * blockDim.x + threadIdx.x;
    if (i >= KN) { keys[(size_t)lb * SORTN + i] = 0xFFFFFFFFFFFFFFFFull; return; }

    float px = over_gen[((size_t)lb * KN + i) * 2 + 0];
    float py = over_gen[((size_t)lb * KN + i) * 2 + 1];
    int x0, y0;
    float wx0, wx1, wy0, wy1;
    ref_coords(px, x0, wx0, wx1);
    ref_coords(py, y0, wy0, wy1);

    const float* r0 = res  + (size_t)lb * NCH * HWSZ;
    const float* o0 = outm + (size_t)lb * NCH * HWSZ;
    int   cxs[4] = {x0, x0 + 1, x0, x0 + 1};
    int   cys[4] = {y0, y0, y0 + 1, y0 + 1};
    float wxs[4] = {wx0, wx1, wx0, wx1};
    float wys[4] = {wy0, wy0, wy1, wy1};

    float acc0 = 0.0f, acc1 = 0.0f;
#pragma unroll
    for (int q = 0; q < 4; ++q) {
        int xq = cxs[q], yq = cys[q];
        if (xq < 0 || xq >= Ww || yq < 0 || yq >= Hh) continue;
        int off = yq * Ww + xq;
        float d0 = opaque(o0[off]            - r0[off]);
        float d1 = opaque(o0[HWSZ + off]     - r0[HWSZ + off]);
        float d2 = opaque(o0[2 * HWSZ + off] - r0[2 * HWSZ + off]);
        float a  = opaque(d0 * d0);
        float bq = opaque(d1 * d1);
        float c  = opaque(d2 * d2);
        float m0 = fmaxf(fmaxf(a, bq), c);
        float m1 = fmaxf(fminf(a, bq), fminf(fmaxf(a, bq), c));
        float wq = opaque(wxs[q] * wys[q]);
        float t0 = opaque(wq * m0);
        float t1 = opaque(wq * m1);
        acc0 = opaque(acc0 + t0);
        acc1 = opaque(acc1 + t1);
    }
    float u = opaque(acc1 - acc0);
    keys[(size_t)lb * SORTN + i] =
        ((uint64_t)sortable_desc32(u) << 32) | (uint32_t)i;
}

// ---------- generalized bitonic sort over per-batch segments ----------
__global__ void __launch_bounds__(1024) bitonic_local_first_g(uint64_t* __restrict__ keys,
                                                              int tile_mask) {
    __shared__ uint64_t sh[2048];
    uint64_t* base = keys + (size_t)blockIdx.x * 2048;
    int t = threadIdx.x;
    sh[t]        = base[t];
    sh[t + 1024] = base[t + 1024];
    __syncthreads();
    int gbase = (blockIdx.x & tile_mask) << 11;
    for (int k = 2; k <= 2048; k <<= 1) {
        for (int j = k >> 1; j >= 1; j >>= 1) {
            int low = t & (j - 1);
            int i = ((t ^ low) << 1) | low;
            int l = i | j;
            bool up = (((gbase + i) & k) == 0);
            uint64_t a = sh[i], c = sh[l];
            if ((a > c) == up) { sh[i] = c; sh[l] = a; }
            __syncthreads();
        }
    }
    base[t]        = sh[t];
    base[t + 1024] = sh[t + 1024];
}

__global__ void bitonic_global_g(uint64_t* __restrict__ keys, int j, int k, int pbits) {
    int t = blockIdx.x * blockDim.x + threadIdx.x;
    int b = t >> pbits;
    int p = t & ((1 << pbits) - 1);
    int low = p & (j - 1);
    int i = ((p ^ low) << 1) | low;
    int l = i | j;
    bool up = ((i & k) == 0);
    uint64_t* kb = keys + ((size_t)b << (pbits + 1));
    uint64_t a = kb[i], c = kb[l];
    if ((a > c) == up) { kb[i] = c; kb[l] = a; }
}

__global__ void __launch_bounds__(1024) bitonic_local_k_g(uint64_t* __restrict__ keys,
                                                          int k, int tile_mask) {
    __shared__ uint64_t sh[2048];
    uint64_t* base = keys + (size_t)blockIdx.x * 2048;
    int t = threadIdx.x;
    sh[t]        = base[t];
    sh[t + 1024] = base[t + 1024];
    __syncthreads();
    int gbase = (blockIdx.x & tile_mask) << 11;
    bool up = ((gbase & k) == 0);
    for (int j = 1024; j >= 1; j >>= 1) {
        int low = t & (j - 1);
        int i = ((t ^ low) << 1) | low;
        int l = i | j;
        uint64_t a = sh[i], c = sh[l];
        if ((a > c) == up) { sh[i] = c; sh[l] = a; }
        __syncthreads();
    }
    base[t]        = sh[t];
    base[t + 1024] = sh[t + 1024];
}

static void run_sort_g(uint64_t* keys, int nb, int seg, hipStream_t stream) {
    int tiles = seg / 2048, tile_mask = tiles - 1;
    int pbits = 31 - __builtin_clz((unsigned)(seg >> 1));
    bitonic_local_first_g<<<nb * tiles, 1024, 0, stream>>>(keys, tile_mask);
    for (int k = 4096; k <= seg; k <<= 1) {
        for (int j = k >> 1; j >= 2048; j >>= 1)
            bitonic_global_g<<<nb * (seg / 2) / 256, 256, 0, stream>>>(keys, j, k, pbits);
        bitonic_local_k_g<<<nb * tiles, 1024, 0, stream>>>(keys, k, tile_mask);
    }
}

// ---------- kernel 2: per-point Morton spatial keys for render reorder ----------
__global__ void pkey_kernel(const uint64_t* __restrict__ keys,
                            const float* __restrict__ over_gen,
                            const float* __restrict__ coverage,
                            uint64_t* __restrict__ pkeys) {
    int lb = blockIdx.y;
    int n  = blockIdx.x * blockDim.x + threadIdx.x;   // < NPT
    float px, py;
    if (n < NIMP) {
        uint32_t idx = (uint32_t)keys[((size_t)lb << 16) + n];
        if (idx >= KN) idx = 0;
        px = over_gen[((size_t)lb * KN + idx) * 2 + 0];
        py = over_gen[((size_t)lb * KN + idx) * 2 + 1];
    } else {
        int m = n - NIMP;
        px = coverage[((size_t)lb * NCOV + m) * 2 + 0];
        py = coverage[((size_t)lb * NCOV + m) * 2 + 1];
    }
    int x0, y0;
    float w0, w1;
    ref_coords(px, x0, w0, w1);
    int xi = x0;
    ref_coords(py, y0, w0, w1);
    int yi = y0;
    xi = min(max(xi, 0), Ww - 1);
    yi = min(max(yi, 0), Hh - 1);
    uint32_t morton = part1by1((uint32_t)xi) | (part1by1((uint32_t)yi) << 1);
    pkeys[(size_t)lb * NPT + n] = ((uint64_t)morton << 32) | (uint32_t)n;
}

// ---------- kernel 3: render (optionally via Morton-sorted point order) ----------
__global__ void render_kernel(const float* __restrict__ x,
                              const float* __restrict__ outm,
                              const float* __restrict__ w_mlp,
                              const float* __restrict__ over_gen,
                              const float* __restrict__ coverage,
                              const uint64_t* __restrict__ keys,
                              const uint64_t* __restrict__ pkeys,  // may be null
                              float* __restrict__ dst) {
    int gid = blockIdx.x * blockDim.x + threadIdx.x;
    int pt = gid >> 3, r = gid & 7;
    int lb = blockIdx.y;
    int n = pt;                                  // output slot
    if (pkeys) n = (uint32_t)pkeys[(size_t)lb * NPT + pt];   // sorted order

    float px, py;
    if (n < NIMP) {
        uint32_t idx = (uint32_t)keys[((size_t)lb << 16) + n];
        if (idx >= KN) idx = 0;
        px = over_gen[((size_t)lb * KN + idx) * 2 + 0];
        py = over_gen[((size_t)lb * KN + idx) * 2 + 1];
    } else {
        int m = n - NIMP;
        px = coverage[((size_t)lb * NCOV + m) * 2 + 0];
        py = coverage[((size_t)lb * NCOV + m) * 2 + 1];
    }

    int x0, y0;
    float wx0, wx1, wy0, wy1;
    ref_coords(px, x0, wx0, wx1);
    ref_coords(py, y0, wy0, wy1);

    int   cxs[4] = {x0, x0 + 1, x0, x0 + 1};
    int   cys[4] = {y0, y0, y0 + 1, y0 + 1};
    float wcs[4] = {wx0 * wy0, wx1 * wy0, wx0 * wy1, wx1 * wy1};
    bool  vld[4];
#pragma unroll
    for (int q = 0; q < 4; ++q)
        vld[q] = (cxs[q] >= 0) & (cxs[q] < Ww) & (cys[q] >= 0) & (cys[q] < Hh);

    float acc0 = 0.0f, acc1 = 0.0f, acc2 = 0.0f;
    for (int c = r; c < NCH + EMBED; c += 8) {
        const float* src = (c < NCH)
            ? (outm + ((size_t)lb * NCH + c) * HWSZ)
            : (x + ((size_t)lb * EMBED + (c - NCH)) * HWSZ);
        float f = 0.0f;
#pragma unroll
        for (int q = 0; q < 4; ++q) {
            if (vld[q]) f += wcs[q] * src[cys[q] * Ww + cxs[q]];
        }
        acc0 += w_mlp[c] * f;
        acc1 += w_mlp[99 + c] * f;
        acc2 += w_mlp[198 + c] * f;
    }
#pragma unroll
    for (int d = 1; d < 8; d <<= 1) {
        acc0 += __shfl_xor(acc0, d);
        acc1 += __shfl_xor(acc1, d);
        acc2 += __shfl_xor(acc2, d);
    }
    if (r == 0) {
        size_t ob = (size_t)lb * 3 * NPT + n;
        dst[ob]           = fmaxf(acc0, 0.0f);
        dst[ob + NPT]     = fmaxf(acc1, 0.0f);
        dst[ob + 2 * NPT] = fmaxf(acc2, 0.0f);
    }
}

extern "C" void kernel_launch(void* const* d_in, const int* in_sizes, int n_in,
                              void* d_out, int out_size, void* d_ws, size_t ws_size,
                              hipStream_t stream) {
    const float* x        = (const float*)d_in[0];
    const float* res      = (const float*)d_in[1];
    const float* outm     = (const float*)d_in[2];
    const float* w_mlp    = (const float*)d_in[3];
    const float* over_gen = (const float*)d_in[4];
    const float* coverage = (const float*)d_in[5];
    float* dst = (float*)d_out;

    const size_t keys_sz = (size_t)Bb * SORTN * sizeof(uint64_t);   // 2 MiB
    const size_t pkey_sz = (size_t)Bb * NPT * sizeof(uint64_t);     // 512 KiB
    const size_t maps_sz = (size_t)Bb * HWSZ * sizeof(float2);      // 8 MiB

    uint64_t* keys = (uint64_t*)d_ws;
    dim3 gU(SORTN / 256, Bb), gP(NPT / 256, Bb), gD(NPT * 8 / 256, Bb);

    if (ws_size >= keys_sz + pkey_sz + maps_sz) {
        uint64_t* pkeys = (uint64_t*)((char*)d_ws + keys_sz);
        float2*   maps  = (float2*)((char*)d_ws + keys_sz + pkey_sz);
        dim3 gM(HWSZ / 256, Bb);
        build_maps<<<gM, 256, 0, stream>>>(res, outm, maps);
        uncert_keys_maps<<<gU, 256, 0, stream>>>(maps, over_gen, keys);
        run_sort_g(keys, Bb, SORTN, stream);
        pkey_kernel<<<gP, 256, 0, stream>>>(keys, over_gen, coverage, pkeys);
        run_sort_g(pkeys, Bb, NPT, stream);
        render_kernel<<<gD, 256, 0, stream>>>(x, outm, w_mlp, over_gen, coverage,
                                              keys, pkeys, dst);
    } else if (ws_size >= keys_sz + pkey_sz) {
        uint64_t* pkeys = (uint64_t*)((char*)d_ws + keys_sz);
        uncert_keys_direct<<<gU, 256, 0, stream>>>(res, outm, over_gen, keys);
        run_sort_g(keys, Bb, SORTN, stream);
        pkey_kernel<<<gP, 256, 0, stream>>>(keys, over_gen, coverage, pkeys);
        run_sort_g(pkeys, Bb, NPT, stream);
        render_kernel<<<gD, 256, 0, stream>>>(x, outm, w_mlp, over_gen, coverage,
                                              keys, pkeys, dst);
    } else {
        // minimal tier: R19 behavior
        uncert_keys_direct<<<gU, 256, 0, stream>>>(res, outm, over_gen, keys);
        run_sort_g(keys, Bb, SORTN, stream);
        render_kernel<<<gD, 256, 0, stream>>>(x, outm, w_mlp, over_gen, coverage,
                                              keys, (const uint64_t*)nullptr, dst);
    }
}